// Round 1
// baseline (475.402 us; speedup 1.0000x reference)
//
#include <hip/hip_runtime.h>
#include <hip/hip_bf16.h>
#include <stdint.h>

// MoE routed GEMM: out[i] = x[i] @ W[e_i] + b[e_i]
// B=8192 tokens, D=2048, E=8 experts. All inputs fp32; compute in bf16 MFMA
// (threshold 1.08e-1 permits bf16; fp8 would not pass).

#define B_TOK 8192
#define DIM   2048
#define NEXP  8
#define BM 128
#define BN 128
#define BK 32

typedef __attribute__((ext_vector_type(4))) float f32x4;
typedef __attribute__((ext_vector_type(8))) short s16x8;

// RNE float->bf16
__device__ __forceinline__ uint16_t f2bf(float f) {
    uint32_t u = __float_as_uint(f);
    uint32_t r = u + 0x7fffu + ((u >> 16) & 1u);
    return (uint16_t)(r >> 16);
}

__device__ __forceinline__ void async16(const void* g, void* l) {
    __builtin_amdgcn_global_load_lds(
        (const __attribute__((address_space(1))) uint32_t*)g,
        (__attribute__((address_space(3))) uint32_t*)l, 16, 0, 0);
}

// ---- routing: histogram -> scan -> scatter -------------------------------
// meta layout (ints): [0..8) counts, [8..16) cursors, [16..25) offsets
__global__ void k_init(int* meta) {
    if (threadIdx.x < 16) meta[threadIdx.x] = 0;
}

__global__ void k_count(const int* __restrict__ idx, int* meta) {
    int i = blockIdx.x * 256 + threadIdx.x;
    if (i < B_TOK) atomicAdd(&meta[idx[i]], 1);
}

__global__ void k_scan(int* meta) {
    if (threadIdx.x == 0) {
        int off = 0;
        for (int e = 0; e < NEXP; ++e) { meta[16 + e] = off; off += meta[e]; }
        meta[16 + NEXP] = off;
    }
}

__global__ void k_scatter(const int* __restrict__ idx, int* meta, int* __restrict__ perm) {
    int i = blockIdx.x * 256 + threadIdx.x;
    if (i < B_TOK) {
        int e = idx[i];
        int pos = atomicAdd(&meta[8 + e], 1);
        perm[meta[16 + e] + pos] = i;
    }
}

// ---- gather x into sorted order, fp32 -> bf16 ----------------------------
// one block per sorted row; 256 thr x 8 elems = 2048
__global__ void k_gather(const float* __restrict__ x, const int* __restrict__ perm,
                         uint16_t* __restrict__ xs) {
    int p = blockIdx.x;
    int t = threadIdx.x;
    int src = perm[p];
    const float4* xin = (const float4*)(x + (size_t)src * DIM);
    float4 a = xin[2 * t];
    float4 c = xin[2 * t + 1];
    uint4 o;
    o.x = (uint32_t)f2bf(a.x) | ((uint32_t)f2bf(a.y) << 16);
    o.y = (uint32_t)f2bf(a.z) | ((uint32_t)f2bf(a.w) << 16);
    o.z = (uint32_t)f2bf(c.x) | ((uint32_t)f2bf(c.y) << 16);
    o.w = (uint32_t)f2bf(c.z) | ((uint32_t)f2bf(c.w) << 16);
    *(uint4*)(xs + (size_t)p * DIM + t * 8) = o;
}

// ---- W[e][d][o] fp32 -> Wt[e][o][d] bf16 (transpose so GEMM B-frag reads
// contiguous k via ds_read_b128) -------------------------------------------
__global__ void k_wt(const float* __restrict__ W, uint16_t* __restrict__ Wt) {
    __shared__ uint16_t tile[64][66];  // +2 pad: transposed reads hit distinct banks
    int e  = blockIdx.z;
    int d0 = blockIdx.x * 64;
    int o0 = blockIdx.y * 64;
    const float* Wp = W + ((size_t)e * DIM + d0) * DIM + o0;
    int c = threadIdx.x & 63, r4 = threadIdx.x >> 6;
    #pragma unroll
    for (int i = 0; i < 16; ++i) {
        int r = i * 4 + r4;
        tile[r][c] = f2bf(Wp[(size_t)r * DIM + c]);  // coalesced fp32 reads
    }
    __syncthreads();
    uint16_t* Wo = Wt + ((size_t)e * DIM + o0) * DIM + d0;
    int c2 = (threadIdx.x & 31) * 2, r8 = threadIdx.x >> 5;
    #pragma unroll
    for (int i = 0; i < 8; ++i) {
        int oo = i * 8 + r8;
        uint32_t v = (uint32_t)tile[c2][oo] | ((uint32_t)tile[c2 + 1][oo] << 16);
        *(uint32_t*)(Wo + (size_t)oo * DIM + c2) = v;  // coalesced 4B stores
    }
}

// ---- per-expert-segment GEMM (m97 structure) -----------------------------
// grid: (DIM/BN, B/BM + NEXP). Block maps blockIdx.y -> (expert, m-tile).
// 4 waves in 2x2; each wave 64x64 out = 4x4 of 16x16x32 bf16 MFMA.
__global__ __launch_bounds__(256) void k_gemm(
    const uint16_t* __restrict__ xs, const uint16_t* __restrict__ Wt,
    const float* __restrict__ bias, const int* __restrict__ meta,
    const int* __restrict__ perm, float* __restrict__ out) {
    __shared__ uint16_t As[BM * BK];   // [m][k] 128x32
    __shared__ uint16_t Bs[BN * BK];   // [n][k] 128x32 (Wt rows)
    __shared__ int permS[BM];

    int id = blockIdx.y;
    int e = -1, seg0 = 0, segc = 0;
    for (int i = 0; i < NEXP; ++i) {
        int o0 = meta[16 + i], o1 = meta[16 + i + 1];
        int tiles = (o1 - o0 + BM - 1) / BM;
        if (id < tiles) { e = i; seg0 = o0; segc = o1 - o0; break; }
        id -= tiles;
    }
    if (e < 0) return;                    // over-provisioned grid tail
    int m0 = seg0 + id * BM;              // sorted-row start of this tile
    int valid = segc - id * BM; if (valid > BM) valid = BM;
    int n0 = blockIdx.x * BN;

    int tid = threadIdx.x;
    if (tid < BM) permS[tid] = (tid < valid) ? perm[m0 + tid] : 0;

    int wave = tid >> 6, lane = tid & 63;
    int wm = (wave >> 1) * 64, wn = (wave & 1) * 64;
    int lr = lane & 15, quad = lane >> 4;

    f32x4 acc[4][4] = {};

    const uint16_t* aG = xs + (size_t)m0 * DIM;
    const uint16_t* bG = Wt + ((size_t)e * DIM + n0) * DIM;

    for (int k0 = 0; k0 < DIM; k0 += BK) {
        // stage 8KB A + 8KB B via width-16 global_load_lds (wave-uniform base + lane*16)
        #pragma unroll
        for (int ro = 0; ro < 2; ++ro) {
            int ch = ro * 256 + tid;
            int row = ch >> 2, kc = (ch & 3) * 8;
            async16(aG + (size_t)row * DIM + k0 + kc, As + ch * 8);
            async16(bG + (size_t)row * DIM + k0 + kc, Bs + ch * 8);
        }
        __syncthreads();  // drains vmcnt -> LDS writes visible

        s16x8 af[4], bf[4];
        #pragma unroll
        for (int i = 0; i < 4; ++i)
            af[i] = *(const s16x8*)(As + (wm + i * 16 + lr) * BK + quad * 8);
        #pragma unroll
        for (int i = 0; i < 4; ++i)
            bf[i] = *(const s16x8*)(Bs + (wn + i * 16 + lr) * BK + quad * 8);
        #pragma unroll
        for (int i = 0; i < 4; ++i)
            #pragma unroll
            for (int j = 0; j < 4; ++j)
                acc[i][j] = __builtin_amdgcn_mfma_f32_16x16x32_bf16(af[i], bf[j], acc[i][j], 0, 0, 0);
        __syncthreads();  // reads done before next stage overwrites
    }

    // epilogue: + bias, scatter rows via perm. C/D layout: col=lane&15, row=quad*4+r
    #pragma unroll
    for (int j = 0; j < 4; ++j) {
        int col = n0 + wn + j * 16 + lr;
        float bv = bias[e * DIM + col];
        #pragma unroll
        for (int i = 0; i < 4; ++i) {
            #pragma unroll
            for (int r = 0; r < 4; ++r) {
                int lrow = wm + i * 16 + quad * 4 + r;
                if (lrow < valid) {
                    out[(size_t)permS[lrow] * DIM + col] = acc[i][j][r] + bv;
                }
            }
        }
    }
}

// ---- launch --------------------------------------------------------------
// ws layout: [0,256) meta | [256, 33024) perm | [64K, +34.1MB) xs (B+BM rows,
// padded so tail-tile staging stays in-bounds) | then Wt (67.1MB). ~96.6 MiB.
extern "C" void kernel_launch(void* const* d_in, const int* in_sizes, int n_in,
                              void* d_out, int out_size, void* d_ws, size_t ws_size,
                              hipStream_t stream) {
    const float* x    = (const float*)d_in[0];
    const float* W    = (const float*)d_in[1];
    const float* bias = (const float*)d_in[2];
    const int*   idx  = (const int*)d_in[3];
    float* out = (float*)d_out;

    char* ws = (char*)d_ws;
    int* meta = (int*)ws;
    int* perm = (int*)(ws + 256);
    uint16_t* xs = (uint16_t*)(ws + 65536);
    uint16_t* Wt = (uint16_t*)(ws + 65536 + (size_t)(B_TOK + BM) * DIM * 2);

    k_init<<<1, 64, 0, stream>>>(meta);
    k_count<<<B_TOK / 256, 256, 0, stream>>>(idx, meta);
    k_scan<<<1, 64, 0, stream>>>(meta);
    k_scatter<<<B_TOK / 256, 256, 0, stream>>>(idx, meta, perm);
    k_gather<<<B_TOK, 256, 0, stream>>>(x, perm, xs);
    k_wt<<<dim3(DIM / 64, DIM / 64, NEXP), 256, 0, stream>>>(W, Wt);
    k_gemm<<<dim3(DIM / BN, B_TOK / BM + NEXP, 1), 256, 0, stream>>>(
        xs, Wt, bias, meta, perm, out);
}